// Round 23
// baseline (113.536 us; speedup 1.0000x reference)
//
#include <hip/hip_runtime.h>
#include <hip/hip_bf16.h>
#include <math.h>

#define BB 4
#define LL 4096
#define DD 512
#define DF 1024
#define CHUNKS 128
#define LC 32  // LL / CHUNKS
#define HALF_ROWS 8192

typedef __bf16 bf16x8 __attribute__((ext_vector_type(8)));
typedef float f32x4 __attribute__((ext_vector_type(4)));

// ---------------- phazor helper ----------------
__device__ inline void get_phazor(const float* __restrict__ pre, const float* __restrict__ pim,
                                  int d, float& ar, float& ai) {
    float pr = pre[d], pi = pim[d];
    float ab = sqrtf(pr * pr + pi * pi);
    float sc = expf(-ab) / ab;
    ar = pr * sc;
    ai = pi * sc;
}

// ---------------- kernel W: coalesced 32x32 tiled transpose f32 -> bf16 ----------------
__global__ __launch_bounds__(256) void k_wt(const float* __restrict__ w1, const float* __restrict__ w2,
                                            __bf16* __restrict__ w1t, __bf16* __restrict__ w2t) {
    __shared__ float tile[32][33];
    const float* src;
    __bf16* dst;
    int R, C;
    if (blockIdx.y == 0) { src = w1; dst = w1t; R = DD; C = DF; }
    else                 { src = w2; dst = w2t; R = DF; C = DD; }
    int ntx = C / 32;
    int c0 = (blockIdx.x % ntx) * 32, r0 = (blockIdx.x / ntx) * 32;
    int tx = threadIdx.x & 31, ty = threadIdx.x >> 5;  // ty in 0..7
#pragma unroll
    for (int i = 0; i < 32; i += 8)
        tile[ty + i][tx] = src[(size_t)(r0 + ty + i) * C + c0 + tx];
    __syncthreads();
#pragma unroll
    for (int i = 0; i < 32; i += 8)
        dst[(size_t)(c0 + ty + i) * R + r0 + tx] = (__bf16)tile[tx][ty + i];
}

// ---------------- kernel B: partial scan with LDS-staged x tile + FUSED row stats --------
__global__ __launch_bounds__(512) void k_scan_partial(
    const float* __restrict__ x,
    const float* __restrict__ pre, const float* __restrict__ pim,
    const float* __restrict__ pinr, const float* __restrict__ pini,
    const float* __restrict__ g, const float* __restrict__ bvec,
    float* __restrict__ carry, float* __restrict__ xstats) {
    __shared__ float xt[LC][DD];     // 64KB
    __shared__ float2 st2[LC];
    int d = threadIdx.x;
    int c = blockIdx.x % CHUNKS, b = blockIdx.x / CHUNKS;
    size_t row0 = (size_t)b * LL + (size_t)c * LC;

    const float4* src4 = reinterpret_cast<const float4*>(x + row0 * DD);
    float4* dst4 = reinterpret_cast<float4*>(&xt[0][0]);
#pragma unroll
    for (int j = 0; j < 8; j++) dst4[d + j * 512] = src4[d + j * 512];
    __syncthreads();

    int wv = d >> 6, lane = d & 63;
#pragma unroll
    for (int rr = 0; rr < 4; rr++) {
        int r = wv * 4 + rr;
        float s = 0.f, q = 0.f;
#pragma unroll
        for (int j = 0; j < 8; j++) {
            float v = xt[r][lane + j * 64];
            s += v; q += v * v;
        }
#pragma unroll
        for (int off = 32; off; off >>= 1) { s += __shfl_xor(s, off); q += __shfl_xor(q, off); }
        if (lane == 0) {
            float m = s * (1.0f / DD);
            float rinv = rsqrtf(q * (1.0f / DD) - m * m + 1e-5f);
            st2[r] = make_float2(m, rinv);
            xstats[(row0 + r) * 2 + 0] = m;
            xstats[(row0 + r) * 2 + 1] = rinv;
        }
    }
    __syncthreads();

    float ar, ai;
    get_phazor(pre, pim, d, ar, ai);
    float pr = pinr[d], pi = pini[d];
    float gd = g[d], bd = bvec[d];
    float hr = 0.f, hi = 0.f;
#pragma unroll
    for (int i = 0; i < LC; i++) {
        float2 s2 = st2[i];
        float xn = (xt[i][d] - s2.x) * s2.y * gd + bd;
        float t = ar * hr - ai * hi + pr * xn;
        hi = ar * hi + ai * hr + pi * xn;
        hr = t;
    }
    size_t idx = ((size_t)blockIdx.x * DD + d) * 2;
    carry[idx] = hr;
    carry[idx + 1] = hi;
}

// ---------------- kernel C: PARALLEL cross-chunk scan, in-place --------
__global__ __launch_bounds__(512) void k_chunk_scan(
    const float* __restrict__ hr0, const float* __restrict__ hi0,
    const float* __restrict__ pre, const float* __restrict__ pim,
    float* __restrict__ carry) {
    int b = blockIdx.x >> 3;
    int dgroup = blockIdx.x & 7;
    int dlocal = threadIdx.x & 63;
    int kt = threadIdx.x >> 6;
    int d = dgroup * 64 + dlocal;
    __shared__ float2 smc[8][64];
    float ar, ai;
    get_phazor(pre, pim, d, ar, ai);
    float Ar = ar, Ai = ai;  // A = a^LC
#pragma unroll
    for (int p = 1; p < LC; p <<= 1) { float t = Ar * Ar - Ai * Ai; Ai = 2.f * Ar * Ai; Ar = t; }
    float Gr = Ar, Gi = Ai;  // G = A^16
#pragma unroll
    for (int p = 0; p < 4; p++) { float t = Gr * Gr - Gi * Gi; Gi = 2.f * Gr * Gi; Gr = t; }
    float2* cp = reinterpret_cast<float2*>(carry);
    size_t base = ((size_t)b * CHUNKS + kt * 16) * DD + d;
    float cr = 0.f, ci = 0.f;
#pragma unroll
    for (int i = 0; i < 16; i++) {
        float2 p2 = cp[base + (size_t)i * DD];
        float t = Ar * cr - Ai * ci + p2.x;
        ci = Ar * ci + Ai * cr + p2.y;
        cr = t;
    }
    smc[kt][dlocal] = make_float2(cr, ci);
    __syncthreads();
    if (kt == 0) {
        float Sr = hr0[b * DD + d], Si = hi0[b * DD + d];
#pragma unroll
        for (int j = 0; j < 8; j++) {
            float2 t2 = smc[j][dlocal];
            smc[j][dlocal] = make_float2(Sr, Si);
            float t = Gr * Sr - Gi * Si + t2.x;
            Si = Gr * Si + Gi * Sr + t2.y;
            Sr = t;
        }
    }
    __syncthreads();
    float2 s0 = smc[kt][dlocal];
    float Sr = s0.x, Si = s0.y;
#pragma unroll
    for (int i = 0; i < 16; i++) {
        float2 p2 = cp[base + (size_t)i * DD];
        cp[base + (size_t)i * DD] = make_float2(Sr, Si);
        float t = Ar * Sr - Ai * Si + p2.x;
        Si = Ar * Si + Ai * Sr + p2.y;
        Sr = t;
    }
}

// ---------------- kernel D: final scan ----------------
// MODE 0: y only. MODE 1: hidden real. MODE 2: hidden interleaved. MODE 3: y + hidden real.
template <int MODE>
__global__ __launch_bounds__(512) void k_scan_out(
    const float* __restrict__ x, const float* __restrict__ xstats,
    const float* __restrict__ pre, const float* __restrict__ pim,
    const float* __restrict__ pinr, const float* __restrict__ pini,
    const float* __restrict__ g, const float* __restrict__ bvec,
    const float* __restrict__ carry_in,
    float* __restrict__ out_y, float* __restrict__ hid) {
    int d = threadIdx.x;
    int c = blockIdx.x % CHUNKS, b = blockIdx.x / CHUNKS;
    float ar, ai;
    get_phazor(pre, pim, d, ar, ai);
    float pr = pinr[d], pi = pini[d];
    float gd = g[d], bd = bvec[d];
    size_t cidx = ((size_t)blockIdx.x * DD + d) * 2;
    float hr = carry_in[cidx], hi = carry_in[cidx + 1];
    int l0 = c * LC;
    const float* xp = x + ((size_t)b * LL + l0) * DD + d;
    const float* st = xstats + ((size_t)b * LL + l0) * 2;
    for (int i = 0; i < LC; i++) {
        float m = st[2 * i], r = st[2 * i + 1];
        float xv = xp[(size_t)i * DD];
        float xn = (xv - m) * r * gd + bd;
        float ur = pr * xn, ui = pi * xn;
        float t = ar * hr - ai * hi + ur;
        hi = ar * hi + ai * hr + ui;
        hr = t;
        size_t row = (size_t)b * LL + l0 + i;
        if constexpr (MODE == 0) {
            out_y[row * DD + d] = hr + xv;
        } else if constexpr (MODE == 1) {
            hid[row * DD + d] = hr;
        } else if constexpr (MODE == 2) {
            reinterpret_cast<float2*>(hid)[row * DD + d] = make_float2(hr, hi);
        } else {
            out_y[row * DD + d] = hr + xv;
            hid[row * DD + d] = hr;
        }
    }
}

// ---------------- kernel E: y -> yn (bf16 normalized) ----------------
__global__ __launch_bounds__(256) void k_ynorm(const float* __restrict__ y,
                                               const float* __restrict__ g, const float* __restrict__ bvec,
                                               __bf16* __restrict__ yn) {
    int wave = threadIdx.x >> 6, lane = threadIdx.x & 63;
    size_t row = (size_t)blockIdx.x * 4 + wave;
    const float4* yr = reinterpret_cast<const float4*>(y + row * DD) + lane * 2;
    float4 a = yr[0], b = yr[1];
    float s = a.x + a.y + a.z + a.w + b.x + b.y + b.z + b.w;
    float q = a.x * a.x + a.y * a.y + a.z * a.z + a.w * a.w +
              b.x * b.x + b.y * b.y + b.z * b.z + b.w * b.w;
#pragma unroll
    for (int off = 32; off; off >>= 1) {
        s += __shfl_xor(s, off);
        q += __shfl_xor(q, off);
    }
    float m = s * (1.0f / DD);
    float r = rsqrtf(q * (1.0f / DD) - m * m + 1e-5f);
    int dbase = lane * 8;
    const float4* gp = reinterpret_cast<const float4*>(g + dbase);
    const float4* bp = reinterpret_cast<const float4*>(bvec + dbase);
    float4 g0 = gp[0], g1 = gp[1], b0 = bp[0], b1 = bp[1];
    bf16x8 o;
    o[0] = (__bf16)((a.x - m) * r * g0.x + b0.x);
    o[1] = (__bf16)((a.y - m) * r * g0.y + b0.y);
    o[2] = (__bf16)((a.z - m) * r * g0.z + b0.z);
    o[3] = (__bf16)((a.w - m) * r * g0.w + b0.w);
    o[4] = (__bf16)((b.x - m) * r * g1.x + b1.x);
    o[5] = (__bf16)((b.y - m) * r * g1.y + b1.y);
    o[6] = (__bf16)((b.z - m) * r * g1.z + b1.z);
    o[7] = (__bf16)((b.w - m) * r * g1.w + b1.w);
    *reinterpret_cast<bf16x8*>(yn + row * DD + dbase) = o;
}

// ---------------- GEMM: r11 structure, BK templated (BK=32 -> 2-3 blocks/CU) --------------
// C[m][n] = A[m][:].Bt[n][:]; EPI 1: silu->bf16, EPI 2: +bias+yadd->f32.
// 8 waves (2M x 4N); double-buffered LDS [R][BK] row-major; 16B-chunk col XOR (row&(CPR-1))
// swizzle on global source AND ds_read (both-sides, rule 21); counted vmcnt(LPT) keeps the
// next tile's loads in flight across both barriers; never vmcnt(0) in the main loop.
template <int BM, int BN, int BK, int KDIM, int NDIM, int EPI>
__global__ __launch_bounds__(512) void k_gemm(
    const __bf16* __restrict__ A, const __bf16* __restrict__ Bt,
    const float* __restrict__ bias, const float* __restrict__ yadd,
    float* __restrict__ outf, __bf16* __restrict__ outb) {
    __shared__ __align__(16) __bf16 As[2][BM * BK];
    __shared__ __align__(16) __bf16 Bs[2][BN * BK];
    constexpr int NT = NDIM / BN;
    constexpr int MR = BM / 32;           // m-frags per wave
    constexpr int NR = BN / 64;           // n-frags per wave
    constexpr int CPR = BK / 8;           // 16B chunks per LDS row
    constexpr int AIT = BM * CPR / 512;   // stage iters (A) per thread
    constexpr int BIT = BN * CPR / 512;   // stage iters (B) per thread
    constexpr int LPT = AIT + BIT;        // loads per thread per K-tile
    constexpr int KSS = BK / 32;          // k-slices per tile
    int nwg = gridDim.x;
    int bid = blockIdx.x;
    int swz = (bid & 7) * (nwg >> 3) + (bid >> 3);
    int m0 = (swz / NT) * BM;
    int n0 = (swz % NT) * BN;
    int tid = threadIdx.x;
    int wid = tid >> 6, lane = tid & 63;

    f32x4 acc[MR][NR] = {};

    int wm = (wid >> 2) * (BM / 2), wn = (wid & 3) * (BN / 4);
    int fr = lane & 15;
    int qbase = lane >> 4;

    auto stage = [&](int buf, int k0) {
#pragma unroll
        for (int i = 0; i < AIT; i++) {
            int c = tid + i * 512;
            int row = c / CPR, kq = c % CPR;
            int kqg = kq ^ (row & (CPR - 1));
            const __bf16* ga = A + (size_t)(m0 + row) * KDIM + k0 + kqg * 8;
            __bf16* la = &As[buf][(size_t)(i * 512 + wid * 64) * 8];
            __builtin_amdgcn_global_load_lds((const __attribute__((address_space(1))) unsigned int*)ga,
                                             (__attribute__((address_space(3))) unsigned int*)la, 16, 0, 0);
        }
#pragma unroll
        for (int i = 0; i < BIT; i++) {
            int c = tid + i * 512;
            int row = c / CPR, kq = c % CPR;
            int kqg = kq ^ (row & (CPR - 1));
            const __bf16* gb = Bt + (size_t)(n0 + row) * KDIM + k0 + kqg * 8;
            __bf16* lb = &Bs[buf][(size_t)(i * 512 + wid * 64) * 8];
            __builtin_amdgcn_global_load_lds((const __attribute__((address_space(1))) unsigned int*)gb,
                                             (__attribute__((address_space(3))) unsigned int*)lb, 16, 0, 0);
        }
    };

    auto compute = [&](int buf) {
#pragma unroll
        for (int ks = 0; ks < KSS; ks++) {
            int q = ks * 4 + qbase;
            bf16x8 af[MR], bfv[NR];
#pragma unroll
            for (int mi = 0; mi < MR; mi++) {
                int R = wm + mi * 16 + fr;
                af[mi] = *reinterpret_cast<const bf16x8*>(
                    &As[buf][R * BK + ((q ^ (R & (CPR - 1))) << 3)]);
            }
#pragma unroll
            for (int ni = 0; ni < NR; ni++) {
                int R = wn + ni * 16 + fr;
                bfv[ni] = *reinterpret_cast<const bf16x8*>(
                    &Bs[buf][R * BK + ((q ^ (R & (CPR - 1))) << 3)]);
            }
            __builtin_amdgcn_s_setprio(1);
#pragma unroll
            for (int mi = 0; mi < MR; mi++)
#pragma unroll
                for (int ni = 0; ni < NR; ni++)
                    acc[mi][ni] = __builtin_amdgcn_mfma_f32_16x16x32_bf16(af[mi], bfv[ni],
                                                                          acc[mi][ni], 0, 0, 0);
            __builtin_amdgcn_s_setprio(0);
        }
    };

    stage(0, 0);
    int cur = 0;
    for (int k0 = BK; k0 < KDIM; k0 += BK) {
        stage(cur ^ 1, k0);  // next tile: stays in flight across the barriers below
        asm volatile("s_waitcnt vmcnt(%0)" ::"i"(LPT) : "memory");
        __builtin_amdgcn_s_barrier();
        compute(cur);
        __builtin_amdgcn_s_barrier();
        cur ^= 1;
    }
    asm volatile("s_waitcnt vmcnt(0)" ::: "memory");
    __builtin_amdgcn_s_barrier();
    compute(cur);

    int orow = (lane >> 4) * 4;
    int ocol = lane & 15;
#pragma unroll
    for (int mi = 0; mi < MR; mi++) {
#pragma unroll
        for (int ni = 0; ni < NR; ni++) {
            int gr = m0 + wm + mi * 16 + orow;
            int gc = n0 + wn + ni * 16 + ocol;
            float bv = bias[gc];
#pragma unroll
            for (int j = 0; j < 4; j++) {
                float v = acc[mi][ni][j] + bv;
                size_t idx = (size_t)(gr + j) * NDIM + gc;
                if constexpr (EPI == 1) {
                    float sv = v / (1.0f + __expf(-v));
                    outb[idx] = (__bf16)sv;
                } else {
                    outf[idx] = v + yadd[idx];
                }
            }
        }
    }
}

// ---------------- launcher ----------------
extern "C" void kernel_launch(void* const* d_in, const int* in_sizes, int n_in,
                              void* d_out, int out_size, void* d_ws, size_t ws_size,
                              hipStream_t stream) {
    const float* x = (const float*)d_in[0];
    const float* hr0 = (const float*)d_in[1];
    const float* hi0 = (const float*)d_in[2];
    const float* pre = (const float*)d_in[3];
    const float* pim = (const float*)d_in[4];
    const float* pinr = (const float*)d_in[5];
    const float* pini = (const float*)d_in[6];
    const float* lng = (const float*)d_in[7];
    const float* lnb = (const float*)d_in[8];
    const float* w1 = (const float*)d_in[9];
    const float* b1 = (const float*)d_in[10];
    const float* w2 = (const float*)d_in[11];
    const float* b2 = (const float*)d_in[12];

    const size_t n = (size_t)BB * LL * DD;  // 8M elements
    const size_t MB1 = 1ull << 20;
    float* outp = (float*)d_out;            // [0, 32MB): y then final out
    char* hidbase = (char*)d_out + n * 4;   // hidden region (>=32MB)
    float* hidp = (float*)hidbase;
    bool interleaved = (out_size >= (int)(3 * n));  // measured: false (hidden = real f32)

    // ws: xstats 128KB | carry 2MB | w1t 1MB | w2t 1MB | staging
    char* ws = (char*)d_ws;
    float* xstats = (float*)ws;      ws += (size_t)BB * LL * 2 * 4;       // 128KB
    float* carry = (float*)ws;       ws += (size_t)BB * CHUNKS * DD * 8;  // 2MB
    __bf16* w1t = (__bf16*)ws;       ws += (size_t)DD * DF * 2;           // 1MB
    __bf16* w2t = (__bf16*)ws;       ws += (size_t)DF * DD * 2;           // 1MB
    char* ws_big = ws;
    const size_t SMALL = ((size_t)128 << 10) + 4 * MB1;   // 4.125MB
    const size_t NEED_FULL = SMALL + 48 * MB1;            // 52.125MB
    const size_t NEED_HALF = SMALL + 24 * MB1;

    // Common prefix (xstats fused into scan_partial)
    k_wt<<<dim3((DD / 32) * (DF / 32), 2), 256, 0, stream>>>(w1, w2, w1t, w2t);
    k_scan_partial<<<BB * CHUNKS, 512, 0, stream>>>(x, pre, pim, pinr, pini, lng, lnb,
                                                    carry, xstats);
    k_chunk_scan<<<BB * 8, 512, 0, stream>>>(hr0, hi0, pre, pim, carry);

    if (!interleaved && ws_size >= NEED_FULL) {
        // Tier A (live path): fused y+hid scan; ynorm; 2 full-size GEMMs (BK=32, 2-3 blk/CU)
        __bf16* yn = (__bf16*)ws_big;
        __bf16* h1 = (__bf16*)(ws_big + 16 * MB1);
        k_scan_out<3><<<BB * CHUNKS, 512, 0, stream>>>(x, xstats, pre, pim, pinr, pini, lng, lnb,
                                                       carry, outp, hidp);
        k_ynorm<<<(BB * LL) / 4, 256, 0, stream>>>(outp, lng, lnb, yn);
        k_gemm<256, 256, 32, DD, DF, 1><<<(BB * LL / 256) * (DF / 256), 512, 0, stream>>>(
            yn, w1t, b1, nullptr, nullptr, h1);
        k_gemm<128, 256, 32, DF, DD, 2><<<(BB * LL / 128) * (DD / 256), 512, 0, stream>>>(
            h1, w2t, b2, outp, outp, nullptr);
    } else if (!interleaved && ws_size >= NEED_HALF) {
        // Tier B: halved staging in ws; fused y+hidden scan
        __bf16* yn_h = (__bf16*)ws_big;
        __bf16* h1_h = (__bf16*)(ws_big + 8 * MB1);
        k_scan_out<3><<<BB * CHUNKS, 512, 0, stream>>>(x, xstats, pre, pim, pinr, pini, lng, lnb,
                                                       carry, outp, hidp);
        for (int h = 0; h < 2; h++) {
            float* yh = outp + (size_t)h * HALF_ROWS * DD;
            k_ynorm<<<HALF_ROWS / 4, 256, 0, stream>>>(yh, lng, lnb, yn_h);
            k_gemm<256, 256, 32, DD, DF, 1><<<(HALF_ROWS / 256) * (DF / 256), 512, 0, stream>>>(
                yn_h, w1t, b1, nullptr, nullptr, h1_h);
            k_gemm<128, 256, 32, DF, DD, 2><<<(HALF_ROWS / 128) * (DD / 256), 512, 0, stream>>>(
                h1_h, w2t, b2, yh, yh, nullptr);
        }
    } else {
        // Tier C: stage FFN inside hidden window; rewrite hidden last
        __bf16* yn_h = (__bf16*)hidbase;
        __bf16* h1_h = (__bf16*)(hidbase + 8 * MB1);
        k_scan_out<0><<<BB * CHUNKS, 512, 0, stream>>>(x, xstats, pre, pim, pinr, pini, lng, lnb,
                                                       carry, outp, nullptr);
        for (int h = 0; h < 2; h++) {
            float* yh = outp + (size_t)h * HALF_ROWS * DD;
            k_ynorm<<<HALF_ROWS / 4, 256, 0, stream>>>(yh, lng, lnb, yn_h);
            k_gemm<256, 256, 32, DD, DF, 1><<<(HALF_ROWS / 256) * (DF / 256), 512, 0, stream>>>(
                yn_h, w1t, b1, nullptr, nullptr, h1_h);
            k_gemm<128, 256, 32, DF, DD, 2><<<(HALF_ROWS / 128) * (DD / 256), 512, 0, stream>>>(
                h1_h, w2t, b2, yh, yh, nullptr);
        }
        if (interleaved) {
            k_scan_out<2><<<BB * CHUNKS, 512, 0, stream>>>(x, xstats, pre, pim, pinr, pini, lng, lnb,
                                                           carry, nullptr, hidp);
        } else {
            k_scan_out<1><<<BB * CHUNKS, 512, 0, stream>>>(x, xstats, pre, pim, pinr, pini, lng, lnb,
                                                           carry, nullptr, hidp);
        }
    }
}

// Round 24
// 107.404 us; speedup vs baseline: 1.0571x; 1.0571x over previous
//
#include <hip/hip_runtime.h>
#include <hip/hip_bf16.h>
#include <math.h>

#define BB 4
#define LL 4096
#define DD 512
#define DF 1024
#define CHUNKS 128
#define LC 32  // LL / CHUNKS
#define HALF_ROWS 8192

typedef __bf16 bf16x8 __attribute__((ext_vector_type(8)));
typedef float f32x4 __attribute__((ext_vector_type(4)));

// ---------------- phazor helper ----------------
__device__ inline void get_phazor(const float* __restrict__ pre, const float* __restrict__ pim,
                                  int d, float& ar, float& ai) {
    float pr = pre[d], pi = pim[d];
    float ab = sqrtf(pr * pr + pi * pi);
    float sc = expf(-ab) / ab;
    ar = pr * sc;
    ai = pi * sc;
}

// ---------------- kernel W: coalesced 32x32 tiled transpose f32 -> bf16 ----------------
__global__ __launch_bounds__(256) void k_wt(const float* __restrict__ w1, const float* __restrict__ w2,
                                            __bf16* __restrict__ w1t, __bf16* __restrict__ w2t) {
    __shared__ float tile[32][33];
    const float* src;
    __bf16* dst;
    int R, C;
    if (blockIdx.y == 0) { src = w1; dst = w1t; R = DD; C = DF; }
    else                 { src = w2; dst = w2t; R = DF; C = DD; }
    int ntx = C / 32;
    int c0 = (blockIdx.x % ntx) * 32, r0 = (blockIdx.x / ntx) * 32;
    int tx = threadIdx.x & 31, ty = threadIdx.x >> 5;  // ty in 0..7
#pragma unroll
    for (int i = 0; i < 32; i += 8)
        tile[ty + i][tx] = src[(size_t)(r0 + ty + i) * C + c0 + tx];
    __syncthreads();
#pragma unroll
    for (int i = 0; i < 32; i += 8)
        dst[(size_t)(c0 + ty + i) * R + r0 + tx] = (__bf16)tile[tx][ty + i];
}

// ---------------- kernel B: partial scan with LDS-staged x tile + FUSED row stats --------
// Block = 512 thr, one chunk (32 rows). Bulk-stage 64KB x-tile -> LDS (1 barrier),
// per-wave row stats from LDS (wave w owns rows 4w..4w+3; pure in-wave shfl; stats ->
// xstats for scan_out), 1 barrier, recurrence reads LDS (consecutive-d, conflict-free).
__global__ __launch_bounds__(512) void k_scan_partial(
    const float* __restrict__ x,
    const float* __restrict__ pre, const float* __restrict__ pim,
    const float* __restrict__ pinr, const float* __restrict__ pini,
    const float* __restrict__ g, const float* __restrict__ bvec,
    float* __restrict__ carry, float* __restrict__ xstats) {
    __shared__ float xt[LC][DD];     // 64KB
    __shared__ float2 st2[LC];
    int d = threadIdx.x;
    int c = blockIdx.x % CHUNKS, b = blockIdx.x / CHUNKS;
    size_t row0 = (size_t)b * LL + (size_t)c * LC;

    // bulk stage: 32 rows x 512 f32 = 4096 float4; 8 per thread, coalesced
    const float4* src4 = reinterpret_cast<const float4*>(x + row0 * DD);
    float4* dst4 = reinterpret_cast<float4*>(&xt[0][0]);
#pragma unroll
    for (int j = 0; j < 8; j++) dst4[d + j * 512] = src4[d + j * 512];
    __syncthreads();

    // per-wave row stats
    int wv = d >> 6, lane = d & 63;
#pragma unroll
    for (int rr = 0; rr < 4; rr++) {
        int r = wv * 4 + rr;
        float s = 0.f, q = 0.f;
#pragma unroll
        for (int j = 0; j < 8; j++) {
            float v = xt[r][lane + j * 64];
            s += v; q += v * v;
        }
#pragma unroll
        for (int off = 32; off; off >>= 1) { s += __shfl_xor(s, off); q += __shfl_xor(q, off); }
        if (lane == 0) {
            float m = s * (1.0f / DD);
            float rinv = rsqrtf(q * (1.0f / DD) - m * m + 1e-5f);
            st2[r] = make_float2(m, rinv);
            xstats[(row0 + r) * 2 + 0] = m;
            xstats[(row0 + r) * 2 + 1] = rinv;
        }
    }
    __syncthreads();

    // recurrence from LDS
    float ar, ai;
    get_phazor(pre, pim, d, ar, ai);
    float pr = pinr[d], pi = pini[d];
    float gd = g[d], bd = bvec[d];
    float hr = 0.f, hi = 0.f;
#pragma unroll
    for (int i = 0; i < LC; i++) {
        float2 s2 = st2[i];
        float xn = (xt[i][d] - s2.x) * s2.y * gd + bd;
        float t = ar * hr - ai * hi + pr * xn;
        hi = ar * hi + ai * hr + pi * xn;
        hr = t;
    }
    size_t idx = ((size_t)blockIdx.x * DD + d) * 2;
    carry[idx] = hr;
    carry[idx + 1] = hi;
}

// ---------------- kernel C: PARALLEL cross-chunk scan (r17/r18 verified), in-place --------
// Grid = BB*8 blocks x 512 thr. Block = 64 dlocal x 8 kt-waves; each kt owns 16 chunks.
__global__ __launch_bounds__(512) void k_chunk_scan(
    const float* __restrict__ hr0, const float* __restrict__ hi0,
    const float* __restrict__ pre, const float* __restrict__ pim,
    float* __restrict__ carry) {
    int b = blockIdx.x >> 3;
    int dgroup = blockIdx.x & 7;
    int dlocal = threadIdx.x & 63;
    int kt = threadIdx.x >> 6;
    int d = dgroup * 64 + dlocal;
    __shared__ float2 smc[8][64];
    float ar, ai;
    get_phazor(pre, pim, d, ar, ai);
    float Ar = ar, Ai = ai;  // A = a^LC
#pragma unroll
    for (int p = 1; p < LC; p <<= 1) { float t = Ar * Ar - Ai * Ai; Ai = 2.f * Ar * Ai; Ar = t; }
    float Gr = Ar, Gi = Ai;  // G = A^16
#pragma unroll
    for (int p = 0; p < 4; p++) { float t = Gr * Gr - Gi * Gi; Gi = 2.f * Gr * Gi; Gr = t; }
    float2* cp = reinterpret_cast<float2*>(carry);
    size_t base = ((size_t)b * CHUNKS + kt * 16) * DD + d;
    float cr = 0.f, ci = 0.f;
#pragma unroll
    for (int i = 0; i < 16; i++) {
        float2 p2 = cp[base + (size_t)i * DD];
        float t = Ar * cr - Ai * ci + p2.x;
        ci = Ar * ci + Ai * cr + p2.y;
        cr = t;
    }
    smc[kt][dlocal] = make_float2(cr, ci);
    __syncthreads();
    if (kt == 0) {
        float Sr = hr0[b * DD + d], Si = hi0[b * DD + d];
#pragma unroll
        for (int j = 0; j < 8; j++) {
            float2 t2 = smc[j][dlocal];
            smc[j][dlocal] = make_float2(Sr, Si);
            float t = Gr * Sr - Gi * Si + t2.x;
            Si = Gr * Si + Gi * Sr + t2.y;
            Sr = t;
        }
    }
    __syncthreads();
    float2 s0 = smc[kt][dlocal];
    float Sr = s0.x, Si = s0.y;
#pragma unroll
    for (int i = 0; i < 16; i++) {
        float2 p2 = cp[base + (size_t)i * DD];
        cp[base + (size_t)i * DD] = make_float2(Sr, Si);
        float t = Ar * Sr - Ai * Si + p2.x;
        Si = Ar * Si + Ai * Sr + p2.y;
        Sr = t;
    }
}

// ---------------- kernel D: final scan (r15/r18 proven, CHUNKS=128) ----------------
// MODE 0: y only. MODE 1: hidden real. MODE 2: hidden interleaved. MODE 3: y + hidden real.
template <int MODE>
__global__ __launch_bounds__(512) void k_scan_out(
    const float* __restrict__ x, const float* __restrict__ xstats,
    const float* __restrict__ pre, const float* __restrict__ pim,
    const float* __restrict__ pinr, const float* __restrict__ pini,
    const float* __restrict__ g, const float* __restrict__ bvec,
    const float* __restrict__ carry_in,
    float* __restrict__ out_y, float* __restrict__ hid) {
    int d = threadIdx.x;
    int c = blockIdx.x % CHUNKS, b = blockIdx.x / CHUNKS;
    float ar, ai;
    get_phazor(pre, pim, d, ar, ai);
    float pr = pinr[d], pi = pini[d];
    float gd = g[d], bd = bvec[d];
    size_t cidx = ((size_t)blockIdx.x * DD + d) * 2;
    float hr = carry_in[cidx], hi = carry_in[cidx + 1];
    int l0 = c * LC;
    const float* xp = x + ((size_t)b * LL + l0) * DD + d;
    const float* st = xstats + ((size_t)b * LL + l0) * 2;
    for (int i = 0; i < LC; i++) {
        float m = st[2 * i], r = st[2 * i + 1];
        float xv = xp[(size_t)i * DD];
        float xn = (xv - m) * r * gd + bd;
        float ur = pr * xn, ui = pi * xn;
        float t = ar * hr - ai * hi + ur;
        hi = ar * hi + ai * hr + ui;
        hr = t;
        size_t row = (size_t)b * LL + l0 + i;
        if constexpr (MODE == 0) {
            out_y[row * DD + d] = hr + xv;
        } else if constexpr (MODE == 1) {
            hid[row * DD + d] = hr;
        } else if constexpr (MODE == 2) {
            reinterpret_cast<float2*>(hid)[row * DD + d] = make_float2(hr, hi);
        } else {
            out_y[row * DD + d] = hr + xv;
            hid[row * DD + d] = hr;
        }
    }
}

// ---------------- kernel E: y -> yn (bf16 normalized) ----------------
__global__ __launch_bounds__(256) void k_ynorm(const float* __restrict__ y,
                                               const float* __restrict__ g, const float* __restrict__ bvec,
                                               __bf16* __restrict__ yn) {
    int wave = threadIdx.x >> 6, lane = threadIdx.x & 63;
    size_t row = (size_t)blockIdx.x * 4 + wave;
    const float4* yr = reinterpret_cast<const float4*>(y + row * DD) + lane * 2;
    float4 a = yr[0], b = yr[1];
    float s = a.x + a.y + a.z + a.w + b.x + b.y + b.z + b.w;
    float q = a.x * a.x + a.y * a.y + a.z * a.z + a.w * a.w +
              b.x * b.x + b.y * b.y + b.z * b.z + b.w * b.w;
#pragma unroll
    for (int off = 32; off; off >>= 1) {
        s += __shfl_xor(s, off);
        q += __shfl_xor(q, off);
    }
    float m = s * (1.0f / DD);
    float r = rsqrtf(q * (1.0f / DD) - m * m + 1e-5f);
    int dbase = lane * 8;
    const float4* gp = reinterpret_cast<const float4*>(g + dbase);
    const float4* bp = reinterpret_cast<const float4*>(bvec + dbase);
    float4 g0 = gp[0], g1 = gp[1], b0 = bp[0], b1 = bp[1];
    bf16x8 o;
    o[0] = (__bf16)((a.x - m) * r * g0.x + b0.x);
    o[1] = (__bf16)((a.y - m) * r * g0.y + b0.y);
    o[2] = (__bf16)((a.z - m) * r * g0.z + b0.z);
    o[3] = (__bf16)((a.w - m) * r * g0.w + b0.w);
    o[4] = (__bf16)((b.x - m) * r * g1.x + b1.x);
    o[5] = (__bf16)((b.y - m) * r * g1.y + b1.y);
    o[6] = (__bf16)((b.z - m) * r * g1.z + b1.z);
    o[7] = (__bf16)((b.w - m) * r * g1.w + b1.w);
    *reinterpret_cast<bf16x8*>(yn + row * DD + dbase) = o;
}

// ---------------- GEMM: round-11 best — 8-wave big-tile, row-major+XOR LDS, counted vmcnt --
template <int BM, int BN, int KDIM, int NDIM, int EPI>
__global__ __launch_bounds__(512) void k_gemm(
    const __bf16* __restrict__ A, const __bf16* __restrict__ Bt,
    const float* __restrict__ bias, const float* __restrict__ yadd,
    float* __restrict__ outf, __bf16* __restrict__ outb) {
    __shared__ __align__(16) __bf16 As[2][BM * 64];
    __shared__ __align__(16) __bf16 Bs[2][BN * 64];
    constexpr int NT = NDIM / BN;
    constexpr int MR = BM / 32;
    constexpr int NR = BN / 64;
    constexpr int LPT = BM / 64 + BN / 64;
    int nwg = gridDim.x;
    int bid = blockIdx.x;
    int swz = (bid & 7) * (nwg >> 3) + (bid >> 3);
    int m0 = (swz / NT) * BM;
    int n0 = (swz % NT) * BN;
    int tid = threadIdx.x;
    int wid = tid >> 6, lane = tid & 63;

    f32x4 acc[MR][NR] = {};

    int wm = (wid >> 2) * (BM / 2), wn = (wid & 3) * (BN / 4);
    int fr = lane & 15;
    int qbase = lane >> 4;

    auto stage = [&](int buf, int k0) {
#pragma unroll
        for (int i = 0; i < BM / 64; i++) {
            int c = tid + i * 512;
            int row = c >> 3, kq = c & 7;
            int kqg = kq ^ (row & 7);
            const __bf16* ga = A + (size_t)(m0 + row) * KDIM + k0 + kqg * 8;
            __bf16* la = &As[buf][(size_t)(i * 512 + wid * 64) * 8];
            __builtin_amdgcn_global_load_lds((const __attribute__((address_space(1))) unsigned int*)ga,
                                             (__attribute__((address_space(3))) unsigned int*)la, 16, 0, 0);
        }
#pragma unroll
        for (int i = 0; i < BN / 64; i++) {
            int c = tid + i * 512;
            int row = c >> 3, kq = c & 7;
            int kqg = kq ^ (row & 7);
            const __bf16* gb = Bt + (size_t)(n0 + row) * KDIM + k0 + kqg * 8;
            __bf16* lb = &Bs[buf][(size_t)(i * 512 + wid * 64) * 8];
            __builtin_amdgcn_global_load_lds((const __attribute__((address_space(1))) unsigned int*)gb,
                                             (__attribute__((address_space(3))) unsigned int*)lb, 16, 0, 0);
        }
    };

    auto compute = [&](int buf) {
#pragma unroll
        for (int ks = 0; ks < 2; ks++) {
            int q = ks * 4 + qbase;
            bf16x8 af[MR], bfv[NR];
#pragma unroll
            for (int mi = 0; mi < MR; mi++) {
                int R = wm + mi * 16 + fr;
                af[mi] = *reinterpret_cast<const bf16x8*>(&As[buf][R * 64 + ((q ^ (R & 7)) << 3)]);
            }
#pragma unroll
            for (int ni = 0; ni < NR; ni++) {
                int R = wn + ni * 16 + fr;
                bfv[ni] = *reinterpret_cast<const bf16x8*>(&Bs[buf][R * 64 + ((q ^ (R & 7)) << 3)]);
            }
            __builtin_amdgcn_s_setprio(1);
#pragma unroll
            for (int mi = 0; mi < MR; mi++)
#pragma unroll
                for (int ni = 0; ni < NR; ni++)
                    acc[mi][ni] = __builtin_amdgcn_mfma_f32_16x16x32_bf16(af[mi], bfv[ni],
                                                                          acc[mi][ni], 0, 0, 0);
            __builtin_amdgcn_s_setprio(0);
        }
    };

    stage(0, 0);
    int cur = 0;
    for (int k0 = 64; k0 < KDIM; k0 += 64) {
        stage(cur ^ 1, k0);  // next tile: stays in flight across the barriers below
        asm volatile("s_waitcnt vmcnt(%0)" ::"i"(LPT) : "memory");
        __builtin_amdgcn_s_barrier();
        compute(cur);
        __builtin_amdgcn_s_barrier();
        cur ^= 1;
    }
    asm volatile("s_waitcnt vmcnt(0)" ::: "memory");
    __builtin_amdgcn_s_barrier();
    compute(cur);

    int orow = (lane >> 4) * 4;
    int ocol = lane & 15;
#pragma unroll
    for (int mi = 0; mi < MR; mi++) {
#pragma unroll
        for (int ni = 0; ni < NR; ni++) {
            int gr = m0 + wm + mi * 16 + orow;
            int gc = n0 + wn + ni * 16 + ocol;
            float bv = bias[gc];
#pragma unroll
            for (int j = 0; j < 4; j++) {
                float v = acc[mi][ni][j] + bv;
                size_t idx = (size_t)(gr + j) * NDIM + gc;
                if constexpr (EPI == 1) {
                    float sv = v / (1.0f + __expf(-v));
                    outb[idx] = (__bf16)sv;
                } else {
                    outf[idx] = v + yadd[idx];
                }
            }
        }
    }
}

// ---------------- launcher ----------------
extern "C" void kernel_launch(void* const* d_in, const int* in_sizes, int n_in,
                              void* d_out, int out_size, void* d_ws, size_t ws_size,
                              hipStream_t stream) {
    const float* x = (const float*)d_in[0];
    const float* hr0 = (const float*)d_in[1];
    const float* hi0 = (const float*)d_in[2];
    const float* pre = (const float*)d_in[3];
    const float* pim = (const float*)d_in[4];
    const float* pinr = (const float*)d_in[5];
    const float* pini = (const float*)d_in[6];
    const float* lng = (const float*)d_in[7];
    const float* lnb = (const float*)d_in[8];
    const float* w1 = (const float*)d_in[9];
    const float* b1 = (const float*)d_in[10];
    const float* w2 = (const float*)d_in[11];
    const float* b2 = (const float*)d_in[12];

    const size_t n = (size_t)BB * LL * DD;  // 8M elements
    const size_t MB1 = 1ull << 20;
    float* outp = (float*)d_out;            // [0, 32MB): y then final out
    char* hidbase = (char*)d_out + n * 4;   // hidden region (>=32MB)
    float* hidp = (float*)hidbase;
    bool interleaved = (out_size >= (int)(3 * n));  // measured: false (hidden = real f32)

    // ws: xstats 128KB | carry 2MB | w1t 1MB | w2t 1MB | staging
    char* ws = (char*)d_ws;
    float* xstats = (float*)ws;      ws += (size_t)BB * LL * 2 * 4;       // 128KB
    float* carry = (float*)ws;       ws += (size_t)BB * CHUNKS * DD * 8;  // 2MB
    __bf16* w1t = (__bf16*)ws;       ws += (size_t)DD * DF * 2;           // 1MB
    __bf16* w2t = (__bf16*)ws;       ws += (size_t)DF * DD * 2;           // 1MB
    char* ws_big = ws;
    const size_t SMALL = ((size_t)128 << 10) + 4 * MB1;   // 4.125MB
    const size_t NEED_FULL = SMALL + 48 * MB1;            // 52.125MB
    const size_t NEED_HALF = SMALL + 24 * MB1;

    // Common prefix (xstats fused into scan_partial)
    k_wt<<<dim3((DD / 32) * (DF / 32), 2), 256, 0, stream>>>(w1, w2, w1t, w2t);
    k_scan_partial<<<BB * CHUNKS, 512, 0, stream>>>(x, pre, pim, pinr, pini, lng, lnb,
                                                    carry, xstats);
    k_chunk_scan<<<BB * 8, 512, 0, stream>>>(hr0, hi0, pre, pim, carry);

    if (!interleaved && ws_size >= NEED_FULL) {
        // Tier A (live path): fused y+hid scan; ynorm; 2 full-size GEMMs
        __bf16* yn = (__bf16*)ws_big;
        __bf16* h1 = (__bf16*)(ws_big + 16 * MB1);
        k_scan_out<3><<<BB * CHUNKS, 512, 0, stream>>>(x, xstats, pre, pim, pinr, pini, lng, lnb,
                                                       carry, outp, hidp);
        k_ynorm<<<(BB * LL) / 4, 256, 0, stream>>>(outp, lng, lnb, yn);
        k_gemm<256, 256, DD, DF, 1><<<(BB * LL / 256) * (DF / 256), 512, 0, stream>>>(
            yn, w1t, b1, nullptr, nullptr, h1);
        k_gemm<128, 256, DF, DD, 2><<<(BB * LL / 128) * (DD / 256), 512, 0, stream>>>(
            h1, w2t, b2, outp, outp, nullptr);
    } else if (!interleaved && ws_size >= NEED_HALF) {
        // Tier B: halved staging in ws; fused y+hidden scan
        __bf16* yn_h = (__bf16*)ws_big;
        __bf16* h1_h = (__bf16*)(ws_big + 8 * MB1);
        k_scan_out<3><<<BB * CHUNKS, 512, 0, stream>>>(x, xstats, pre, pim, pinr, pini, lng, lnb,
                                                       carry, outp, hidp);
        for (int h = 0; h < 2; h++) {
            float* yh = outp + (size_t)h * HALF_ROWS * DD;
            k_ynorm<<<HALF_ROWS / 4, 256, 0, stream>>>(yh, lng, lnb, yn_h);
            k_gemm<256, 256, DD, DF, 1><<<(HALF_ROWS / 256) * (DF / 256), 512, 0, stream>>>(
                yn_h, w1t, b1, nullptr, nullptr, h1_h);
            k_gemm<128, 256, DF, DD, 2><<<(HALF_ROWS / 128) * (DD / 256), 512, 0, stream>>>(
                h1_h, w2t, b2, yh, yh, nullptr);
        }
    } else {
        // Tier C: stage FFN inside hidden window; rewrite hidden last
        __bf16* yn_h = (__bf16*)hidbase;
        __bf16* h1_h = (__bf16*)(hidbase + 8 * MB1);
        k_scan_out<0><<<BB * CHUNKS, 512, 0, stream>>>(x, xstats, pre, pim, pinr, pini, lng, lnb,
                                                       carry, outp, nullptr);
        for (int h = 0; h < 2; h++) {
            float* yh = outp + (size_t)h * HALF_ROWS * DD;
            k_ynorm<<<HALF_ROWS / 4, 256, 0, stream>>>(yh, lng, lnb, yn_h);
            k_gemm<256, 256, DD, DF, 1><<<(HALF_ROWS / 256) * (DF / 256), 512, 0, stream>>>(
                yn_h, w1t, b1, nullptr, nullptr, h1_h);
            k_gemm<128, 256, DF, DD, 2><<<(HALF_ROWS / 128) * (DD / 256), 512, 0, stream>>>(
                h1_h, w2t, b2, yh, yh, nullptr);
        }
        if (interleaved) {
            k_scan_out<2><<<BB * CHUNKS, 512, 0, stream>>>(x, xstats, pre, pim, pinr, pini, lng, lnb,
                                                           carry, nullptr, hidp);
        } else {
            k_scan_out<1><<<BB * CHUNKS, 512, 0, stream>>>(x, xstats, pre, pim, pinr, pini, lng, lnb,
                                                           carry, nullptr, hidp);
        }
    }
}